// Round 2
// baseline (618.537 us; speedup 1.0000x reference)
//
#include <hip/hip_runtime.h>

#define HIDDEN 2048
#define HEAD_DIM 128
#define NUM_KV 8
#define BATCH 32
#define MAX_PAGES 128
#define PAGE 16
#define QKV_COLS 4096          // 2048 q | 1024 k | 1024 v
#define KSPLIT1 16
#define KCH1 (HIDDEN / KSPLIT1)   // 128
#define CSPLIT 8
#define PAGES_PER_SPLIT (MAX_PAGES / CSPLIT)  // 16
#define KSPLIT2 16
#define KCH2 (HIDDEN / KSPLIT2)   // 128

// ws layout (float offsets). Regions reused across sequential phases.
#define WS_QKVP 0                 // 16*32*4096 = 2097152
#define WS_QBUF 2097152           // 65536 (q post norm+rope, f32)
#define WS_AOUT 2162688           // 65536 (attn output, f32)
#define WS_PACC 0                 // 32*8*8*256 = 524288 (reuses QKVP region)
#define WS_PML  524288            // 32*8*8*4 = 8192
#define WS_OUTP 0                 // 16*65536 = 1048576 (reuses again)
// high-water: 2228224 floats = 8.5 MB

// --- kernel 1: QKV projection partials. grid (32 colblocks, KSPLIT1), 128 thr ---
__global__ __launch_bounds__(128) void qkv_partial_kernel(
    const float* __restrict__ x, const float* __restrict__ wq,
    const float* __restrict__ wk, const float* __restrict__ wv,
    float* __restrict__ part) {
  int n = blockIdx.x * 128 + threadIdx.x;   // 0..4095
  int kz = blockIdx.y;
  int k0 = kz * KCH1;
  const float* W; int ldw, col;             // block-uniform branch (128-col blocks)
  if (n < 2048)      { W = wq; ldw = 2048; col = n; }
  else if (n < 3072) { W = wk; ldw = 1024; col = n - 2048; }
  else               { W = wv; ldw = 1024; col = n - 3072; }
  float acc[BATCH];
#pragma unroll
  for (int b = 0; b < BATCH; ++b) acc[b] = 0.f;
#pragma unroll 4
  for (int kk = 0; kk < KCH1; ++kk) {
    int k = k0 + kk;
    float w = W[(size_t)k * ldw + col];
#pragma unroll
    for (int b = 0; b < BATCH; ++b)
      acc[b] = fmaf(x[b * HIDDEN + k], w, acc[b]);   // x[] wave-uniform -> s_load
  }
#pragma unroll
  for (int b = 0; b < BATCH; ++b)
    part[((size_t)kz * BATCH + b) * QKV_COLS + n] = acc[b];
}

// --- kernel 2: reduce partials, rmsnorm + rope, emit q(ws f32), k,v (d_out f32) ---
// grid (32 batch, 32 slots: 16 q heads, 8 k heads, 8 v heads), 128 thr
__global__ __launch_bounds__(128) void qkv_finish_kernel(
    const float* __restrict__ part, const float* __restrict__ cosb,
    const float* __restrict__ sinb, const float* __restrict__ qnw,
    const float* __restrict__ knw, float* __restrict__ qbuf,
    float* __restrict__ outk, float* __restrict__ outv) {
  int b = blockIdx.x;
  int s = blockIdx.y;
  int d = threadIdx.x;
  int col;
  if (s < 16)      col = s * 128 + d;
  else if (s < 24) col = 2048 + (s - 16) * 128 + d;
  else             col = 3072 + (s - 24) * 128 + d;
  float val = 0.f;
#pragma unroll
  for (int z = 0; z < KSPLIT1; ++z)
    val += part[((size_t)z * BATCH + b) * QKV_COLS + col];
  if (s >= 24) {  // v: raw projection, straight to output (block-uniform branch)
    outv[b * 1024 + (s - 24) * 128 + d] = val;
    return;
  }
  __shared__ float red[128];
  __shared__ float xs[128];
  red[d] = val * val;
  __syncthreads();
#pragma unroll
  for (int st = 64; st > 0; st >>= 1) {
    if (d < st) red[d] += red[d + st];
    __syncthreads();
  }
  float var = red[0] * (1.f / 128.f);
  float inv = rsqrtf(var + 1e-6f);
  const float* nw = (s < 16) ? qnw : knw;
  float xn = val * inv * nw[d];
  xs[d] = xn;
  __syncthreads();
  float c  = cosb[b * 128 + d];
  float sn = sinb[b * 128 + d];
  float rot = (d < 64) ? -xs[d + 64] : xs[d - 64];
  float o = xn * c + rot * sn;
  if (s < 16) qbuf[b * 2048 + s * 128 + d] = o;
  else        outk[b * 1024 + (s - 16) * 128 + d] = o;
}

// --- kernel 3: flash-decode attention. grid (32, 8 kvh, 8 splits), 256 thr ---
__global__ __launch_bounds__(256) void attn_kernel(
    const float* __restrict__ qbuf, const float* __restrict__ kc,
    const float* __restrict__ vc, const int* __restrict__ btab,
    const int* __restrict__ clen, float* __restrict__ pacc,
    float* __restrict__ pml) {
  int b = blockIdx.x, g = blockIdx.y, sp = blockIdx.z;
  int tid = threadIdx.x;
  __shared__ float v_s[PAGE][HEAD_DIM];
  __shared__ float s_s[2][PAGE];
  const float NEG_INF = -__builtin_huge_valf();
  int ctx = clen[b];
  int npages = (ctx + PAGE - 1) >> 4;
  int p0 = sp * PAGES_PER_SPLIT;
  int p1 = min(p0 + PAGES_PER_SPLIT, npages);

  int pos = tid >> 4, dp = tid & 15;       // dot/load phase mapping
  float ql0[8], ql1[8];
  {
    const float4* q0 = (const float4*)(qbuf + b * 2048 + (g * 2 + 0) * 128 + dp * 8);
    const float4* q1 = (const float4*)(qbuf + b * 2048 + (g * 2 + 1) * 128 + dp * 8);
    float4 a = q0[0], c = q0[1];
    ql0[0]=a.x; ql0[1]=a.y; ql0[2]=a.z; ql0[3]=a.w;
    ql0[4]=c.x; ql0[5]=c.y; ql0[6]=c.z; ql0[7]=c.w;
    a = q1[0]; c = q1[1];
    ql1[0]=a.x; ql1[1]=a.y; ql1[2]=a.z; ql1[3]=a.w;
    ql1[4]=c.x; ql1[5]=c.y; ql1[6]=c.z; ql1[7]=c.w;
  }
  int r2 = tid >> 7, d2 = tid & 127;       // accumulate phase mapping
  float acc = 0.f, lsum = 0.f, m = NEG_INF;
  const float scale = 0.08838834764831845f;

  for (int p = p0; p < p1; ++p) {
    int page = btab[b * MAX_PAGES + p];
    size_t base = ((size_t)(page * PAGE + pos) * NUM_KV + g) * HEAD_DIM + dp * 8;
    const float4* kp = (const float4*)(kc + base);
    const float4* vp = (const float4*)(vc + base);
    float4 k0 = kp[0], k1 = kp[1];
    float4 v0 = vp[0], v1 = vp[1];
    float s0 = 0.f, s1 = 0.f;
    s0 = fmaf(k0.x, ql0[0], s0); s1 = fmaf(k0.x, ql1[0], s1);
    s0 = fmaf(k0.y, ql0[1], s0); s1 = fmaf(k0.y, ql1[1], s1);
    s0 = fmaf(k0.z, ql0[2], s0); s1 = fmaf(k0.z, ql1[2], s1);
    s0 = fmaf(k0.w, ql0[3], s0); s1 = fmaf(k0.w, ql1[3], s1);
    s0 = fmaf(k1.x, ql0[4], s0); s1 = fmaf(k1.x, ql1[4], s1);
    s0 = fmaf(k1.y, ql0[5], s0); s1 = fmaf(k1.y, ql1[5], s1);
    s0 = fmaf(k1.z, ql0[6], s0); s1 = fmaf(k1.z, ql1[6], s1);
    s0 = fmaf(k1.w, ql0[7], s0); s1 = fmaf(k1.w, ql1[7], s1);
#pragma unroll
    for (int off = 1; off < 16; off <<= 1) {
      s0 += __shfl_xor(s0, off);
      s1 += __shfl_xor(s1, off);
    }
    *(float4*)(&v_s[pos][dp * 8])     = v0;
    *(float4*)(&v_s[pos][dp * 8 + 4]) = v1;
    if (dp == 0) {
      bool valid = (p * PAGE + pos) < ctx;
      s_s[0][pos] = valid ? s0 * scale : NEG_INF;
      s_s[1][pos] = valid ? s1 * scale : NEG_INF;
    }
    __syncthreads();
    const float* srow = s_s[r2];
    float cmax = NEG_INF;
#pragma unroll
    for (int l = 0; l < PAGE; ++l) cmax = fmaxf(cmax, srow[l]);
    float mnew = fmaxf(m, cmax);            // cmax finite: pos 0 of any page < npages is valid
    float alpha = __expf(m - mnew);         // m=-inf first iter -> 0
    acc *= alpha; lsum *= alpha;
#pragma unroll
    for (int l = 0; l < PAGE; ++l) {
      float w = __expf(srow[l] - mnew);     // masked -inf -> 0
      lsum += w;
      acc = fmaf(w, v_s[l][d2], acc);
    }
    m = mnew;
    __syncthreads();
  }
  size_t pidx = ((size_t)b * NUM_KV + g) * CSPLIT + sp;
  pacc[pidx * 256 + tid] = acc;
  if (d2 == 0) {
    pml[pidx * 4 + r2 * 2 + 0] = m;
    pml[pidx * 4 + r2 * 2 + 1] = lsum;
  }
}

// --- kernel 4: merge splits. grid (32, 8), 256 thr ---
__global__ __launch_bounds__(256) void attn_combine_kernel(
    const float* __restrict__ pacc, const float* __restrict__ pml,
    float* __restrict__ attn_out) {
  int b = blockIdx.x, g = blockIdx.y, tid = threadIdx.x;
  int r = tid >> 7, d = tid & 127;
  size_t base = ((size_t)b * NUM_KV + g) * CSPLIT;
  float M = -__builtin_huge_valf();
#pragma unroll
  for (int s = 0; s < CSPLIT; ++s)
    M = fmaxf(M, pml[(base + s) * 4 + r * 2]);
  float accT = 0.f, lT = 0.f;
#pragma unroll
  for (int s = 0; s < CSPLIT; ++s) {
    float ms = pml[(base + s) * 4 + r * 2];
    float ls = pml[(base + s) * 4 + r * 2 + 1];
    float w = __expf(ms - M);          // empty split: exp(-inf)=0
    accT = fmaf(w, pacc[(base + s) * 256 + tid], accT);
    lT = fmaf(w, ls, lT);
  }
  attn_out[b * 2048 + (g * 2 + r) * 128 + d] = accT / lT;   // lT >= 1
}

// --- kernel 5: output projection partials. grid (16 colblocks, KSPLIT2), 128 thr ---
__global__ __launch_bounds__(128) void out_partial_kernel(
    const float* __restrict__ ain, const float* __restrict__ wo,
    float* __restrict__ part) {
  int n = blockIdx.x * 128 + threadIdx.x;  // 0..2047
  int kz = blockIdx.y;
  int k0 = kz * KCH2;
  float acc[BATCH];
#pragma unroll
  for (int b = 0; b < BATCH; ++b) acc[b] = 0.f;
#pragma unroll 4
  for (int kk = 0; kk < KCH2; ++kk) {
    int k = k0 + kk;
    float w = wo[(size_t)k * HIDDEN + n];
#pragma unroll
    for (int b = 0; b < BATCH; ++b)
      acc[b] = fmaf(ain[b * HIDDEN + k], w, acc[b]);  // uniform -> s_load
  }
#pragma unroll
  for (int b = 0; b < BATCH; ++b)
    part[(size_t)kz * (BATCH * HIDDEN) + b * HIDDEN + n] = acc[b];
}

// --- kernel 6: reduce + store f32 output. grid (256), 256 thr ---
__global__ __launch_bounds__(256) void out_finish_kernel(
    const float* __restrict__ part, float* __restrict__ outp) {
  int idx = blockIdx.x * 256 + threadIdx.x;  // 0..65535
  float v = 0.f;
#pragma unroll
  for (int z = 0; z < KSPLIT2; ++z)
    v += part[(size_t)z * (BATCH * HIDDEN) + idx];
  outp[idx] = v;
}

extern "C" void kernel_launch(void* const* d_in, const int* in_sizes, int n_in,
                              void* d_out, int out_size, void* d_ws, size_t ws_size,
                              hipStream_t stream) {
  const float* hidden = (const float*)d_in[0];
  const float* cosb   = (const float*)d_in[1];
  const float* sinb   = (const float*)d_in[2];
  const float* kc     = (const float*)d_in[3];
  const float* vc     = (const float*)d_in[4];
  const float* wq     = (const float*)d_in[5];
  const float* wk     = (const float*)d_in[6];
  const float* wv     = (const float*)d_in[7];
  const float* wo     = (const float*)d_in[8];
  const float* qnw    = (const float*)d_in[9];
  const float* knw    = (const float*)d_in[10];
  const int* btab     = (const int*)d_in[11];
  const int* clen     = (const int*)d_in[12];
  float* out = (float*)d_out;
  float* ws  = (float*)d_ws;

  float* qkvp = ws + WS_QKVP;
  float* qbuf = ws + WS_QBUF;
  float* aout = ws + WS_AOUT;
  float* pacc = ws + WS_PACC;
  float* pml  = ws + WS_PML;
  float* outp = ws + WS_OUTP;

  float* outO = out;             // [32,2048]
  float* outK = out + 65536;     // [32,8,128]
  float* outV = out + 98304;     // [32,8,128]

  hipLaunchKernelGGL(qkv_partial_kernel, dim3(32, KSPLIT1), dim3(128), 0, stream,
                     hidden, wq, wk, wv, qkvp);
  hipLaunchKernelGGL(qkv_finish_kernel, dim3(32, 32), dim3(128), 0, stream,
                     qkvp, cosb, sinb, qnw, knw, qbuf, outK, outV);
  hipLaunchKernelGGL(attn_kernel, dim3(BATCH, NUM_KV, CSPLIT), dim3(256), 0, stream,
                     qbuf, kc, vc, btab, clen, pacc, pml);
  hipLaunchKernelGGL(attn_combine_kernel, dim3(BATCH, NUM_KV), dim3(256), 0, stream,
                     pacc, pml, aout);
  hipLaunchKernelGGL(out_partial_kernel, dim3(16, KSPLIT2), dim3(128), 0, stream,
                     aout, wo, outp);
  hipLaunchKernelGGL(out_finish_kernel, dim3(256), dim3(256), 0, stream,
                     outp, outO);
}